// Round 5
// baseline (16013.933 us; speedup 1.0000x reference)
//
#include <hip/hip_runtime.h>
#include <hip/hip_cooperative_groups.h>

namespace cg = cooperative_groups;

#define IN_DIM 1024
#define HD 256
#define G4H 1024
#define BB 64
#define TT 512
#define NCLS 8

/* h rings: 3 layers x 16 slots x [k][b] */
#define RING 16
#define SLOT_STRIDE (HD * BB)             /* 16384 floats */
#define LAYER_STRIDE (RING * SLOT_STRIDE) /* 262144 floats */

__device__ __forceinline__ float sigmoidf_(float x) {
    return 1.0f / (1.0f + __expf(-x));
}
__device__ __forceinline__ float tanhf_(float x) {
    return 2.0f / (1.0f + __expf(-2.0f * x)) - 1.0f;
}
__device__ __forceinline__ float ld_agent(const float* p) {
    return __hip_atomic_load(p, __ATOMIC_RELAXED, __HIP_MEMORY_SCOPE_AGENT);
}
__device__ __forceinline__ void st_agent(float* p, float v) {
    __hip_atomic_store(p, v, __ATOMIC_RELAXED, __HIP_MEMORY_SCOPE_AGENT);
}
__device__ __forceinline__ int ld_flag(const int* p) {
    return __hip_atomic_load(p, __ATOMIC_RELAXED, __HIP_MEMORY_SCOPE_AGENT);
}
__device__ __forceinline__ void st_flag_rel(int* p, int v) {
    __hip_atomic_store(p, v, __ATOMIC_RELEASE, __HIP_MEMORY_SCOPE_AGENT);
}

/* every lane checks 4 of the 256 per-wave flags (coalesced 256B loads) */
__device__ __forceinline__ void poll256(const int* f, int need, int b) {
    const int* p0 = f + b;
    const int* p1 = f + 64 + b;
    const int* p2 = f + 128 + b;
    const int* p3 = f + 192 + b;
    for (;;) {
        int m = min(min(ld_flag(p0), ld_flag(p1)), min(ld_flag(p2), ld_flag(p3)));
        if (__all(m >= need)) break;
        __builtin_amdgcn_s_sleep(1);
    }
    __atomic_signal_fence(__ATOMIC_SEQ_CST);
}

/* ---------------- Kernel 1: xgX[t][n][b] = (x @ Wih0^T + b0), M re-indexed as t*64+b ---------------- */
#define GBM 128
#define GBN 128
#define GBK 16

__global__ __launch_bounds__(256) void xg0_gemm(const float* __restrict__ x,
                                                const float* __restrict__ Wih0,
                                                const float* __restrict__ b0,
                                                float* __restrict__ xgX) {
    __shared__ float As[GBK][GBM];
    __shared__ float Bs[GBK][GBN];
    const int m0 = blockIdx.y * GBM;    /* m' = t*64 + b */
    const int n0 = blockIdx.x * GBN;
    const int tid = threadIdx.x;
    const int tx = tid & 15;
    const int ty = tid >> 4;
    const int lr = tid >> 1;
    const int lk = (tid & 1) * 8;
    const int mrow = m0 + lr;
    const size_t arow = ((size_t)(mrow & 63) * TT + (mrow >> 6)) * IN_DIM;  /* x row (b*T + t) */
    float acc[8][8] = {};
    for (int k0 = 0; k0 < IN_DIM; k0 += GBK) {
        const float4 a0 = *(const float4*)&x[arow + k0 + lk];
        const float4 a1 = *(const float4*)&x[arow + k0 + lk + 4];
        const float4 w0 = *(const float4*)&Wih0[(size_t)(n0 + lr) * IN_DIM + k0 + lk];
        const float4 w1 = *(const float4*)&Wih0[(size_t)(n0 + lr) * IN_DIM + k0 + lk + 4];
        __syncthreads();
        As[lk + 0][lr] = a0.x; As[lk + 1][lr] = a0.y; As[lk + 2][lr] = a0.z; As[lk + 3][lr] = a0.w;
        As[lk + 4][lr] = a1.x; As[lk + 5][lr] = a1.y; As[lk + 6][lr] = a1.z; As[lk + 7][lr] = a1.w;
        Bs[lk + 0][lr] = w0.x; Bs[lk + 1][lr] = w0.y; Bs[lk + 2][lr] = w0.z; Bs[lk + 3][lr] = w0.w;
        Bs[lk + 4][lr] = w1.x; Bs[lk + 5][lr] = w1.y; Bs[lk + 6][lr] = w1.z; Bs[lk + 7][lr] = w1.w;
        __syncthreads();
#pragma unroll
        for (int k = 0; k < GBK; ++k) {
            const float4 av0 = *(const float4*)&As[k][ty * 8];
            const float4 av1 = *(const float4*)&As[k][ty * 8 + 4];
            const float4 bv0 = *(const float4*)&Bs[k][tx * 8];
            const float4 bv1 = *(const float4*)&Bs[k][tx * 8 + 4];
            const float am[8] = {av0.x, av0.y, av0.z, av0.w, av1.x, av1.y, av1.z, av1.w};
            const float bn[8] = {bv0.x, bv0.y, bv0.z, bv0.w, bv1.x, bv1.y, bv1.z, bv1.w};
#pragma unroll
            for (int i = 0; i < 8; ++i)
#pragma unroll
                for (int jj = 0; jj < 8; ++jj)
                    acc[i][jj] = fmaf(am[i], bn[jj], acc[i][jj]);
        }
    }
    float bias[8];
#pragma unroll
    for (int jj = 0; jj < 8; ++jj) bias[jj] = b0[n0 + tx * 8 + jj];
#pragma unroll
    for (int i = 0; i < 8; ++i) {
        const int mr = m0 + ty * 8 + i;
        const int bb_ = mr & 63;
        const int tt_ = mr >> 6;
        float* crow = xgX + (size_t)tt_ * G4H * BB + bb_;
#pragma unroll
        for (int jj = 0; jj < 8; ++jj)
            crow[(size_t)(n0 + tx * 8 + jj) * BB] = acc[i][jj] + bias[jj];
    }
}

/* ---------------- Kernel 2: barrier-free, per-wave flag-synced 3-layer LSTM ----------------
 * 192 blocks = 3 layers x 64; 256 threads = 4 waves. Wave = one j (full 512-K dot for
 * all 4 gates, lane = b). Weights via readfirstlane-uniform pointers (scalar-cached
 * plain loads). h exchange via sc1 (LLC-coherent). One release flag per wave per tick.
 * NO __syncthreads in the tick loop. */
__device__ __forceinline__ void dot4(const float* __restrict__ r0, const float* __restrict__ r1,
                                     const float* __restrict__ r2, const float* __restrict__ r3,
                                     const float* __restrict__ hs, int b, float4& A) {
#pragma unroll 4
    for (int k0 = 0; k0 < HD; k0 += 8) {
        float hv[8];
#pragma unroll
        for (int u = 0; u < 8; ++u) hv[u] = ld_agent(&hs[(k0 + u) * BB + b]);
#pragma unroll
        for (int u = 0; u < 8; u += 4) {
            const float4 w0 = *(const float4*)&r0[k0 + u];
            const float4 w1 = *(const float4*)&r1[k0 + u];
            const float4 w2 = *(const float4*)&r2[k0 + u];
            const float4 w3 = *(const float4*)&r3[k0 + u];
            A.x = fmaf(w0.x, hv[u], A.x); A.x = fmaf(w0.y, hv[u + 1], A.x);
            A.x = fmaf(w0.z, hv[u + 2], A.x); A.x = fmaf(w0.w, hv[u + 3], A.x);
            A.y = fmaf(w1.x, hv[u], A.y); A.y = fmaf(w1.y, hv[u + 1], A.y);
            A.y = fmaf(w1.z, hv[u + 2], A.y); A.y = fmaf(w1.w, hv[u + 3], A.y);
            A.z = fmaf(w2.x, hv[u], A.z); A.z = fmaf(w2.y, hv[u + 1], A.z);
            A.z = fmaf(w2.z, hv[u + 2], A.z); A.z = fmaf(w2.w, hv[u + 3], A.z);
            A.w = fmaf(w3.x, hv[u], A.w); A.w = fmaf(w3.y, hv[u + 1], A.w);
            A.w = fmaf(w3.z, hv[u + 2], A.w); A.w = fmaf(w3.w, hv[u + 3], A.w);
        }
    }
}

__global__ __launch_bounds__(256) void lstm_cells(
    const float* __restrict__ xgX,
    const float* __restrict__ Whh0,
    const float* __restrict__ Wih1, const float* __restrict__ Whh1, const float* __restrict__ b1,
    const float* __restrict__ Wih2, const float* __restrict__ Whh2, const float* __restrict__ b2,
    float* __restrict__ hring, int* __restrict__ prog)
{
    cg::grid_group grid = cg::this_grid();
    const int blk = blockIdx.x;
    const int layer = blk >> 6;
    const int lb = blk & 63;
    const int tid = threadIdx.x;
    const int w = tid >> 6;
    const int b = tid & 63;
    const int j = __builtin_amdgcn_readfirstlane(lb * 4 + w);   /* wave-uniform j */

    /* zero flags (ws poisoned); rings need no zeroing (t=0 skips h[t-1]) */
    for (int i = blk * 256 + tid; i < 3 * 256; i += 192 * 256) prog[i] = 0;

    const float* Wih = (layer == 1) ? Wih1 : Wih2;
    const float* Whh = (layer == 0) ? Whh0 : ((layer == 1) ? Whh1 : Whh2);
    const float* bias = (layer == 1) ? b1 : b2;

    const float* wi0 = Wih + (size_t)(0 * HD + j) * HD;
    const float* wi1 = Wih + (size_t)(1 * HD + j) * HD;
    const float* wi2 = Wih + (size_t)(2 * HD + j) * HD;
    const float* wi3 = Wih + (size_t)(3 * HD + j) * HD;
    const float* wh0 = Whh + (size_t)(0 * HD + j) * HD;
    const float* wh1 = Whh + (size_t)(1 * HD + j) * HD;
    const float* wh2 = Whh + (size_t)(2 * HD + j) * HD;
    const float* wh3 = Whh + (size_t)(3 * HD + j) * HD;

    float bs0 = 0.f, bs1 = 0.f, bs2 = 0.f, bs3 = 0.f;
    if (layer > 0) {
        bs0 = bias[0 * HD + j]; bs1 = bias[1 * HD + j];
        bs2 = bias[2 * HD + j]; bs3 = bias[3 * HD + j];
    }

    float* myring = hring + layer * LAYER_STRIDE;
    const float* inring = hring + (layer - 1) * LAYER_STRIDE;
    int* prog_own = prog + layer * 256;
    const int* prog_in = prog + (layer - 1) * 256;
    const int* prog_nxt = prog + (layer + 1) * 256;

    float c = 0.0f;

    grid.sync();   /* flags zeroed, visible device-wide */

    for (int t = 0; t < TT; ++t) {
        /* ring-reuse guard: every 8 ticks make sure consumers are within 8 of us */
        if (layer < 2 && t >= RING && (t & 7) == 0) poll256(prog_nxt, t - 8, b);

        float4 A;
        /* phase 1: input contribution (depends only on producer layer) */
        if (layer == 0) {
            const float* xg = xgX + (size_t)t * G4H * BB + (size_t)j * BB + b;
            A.x = xg[0 * 16384]; A.y = xg[1 * 16384];
            A.z = xg[2 * 16384]; A.w = xg[3 * 16384];
        } else {
            poll256(prog_in, t + 1, b);
            A.x = bs0; A.y = bs1; A.z = bs2; A.w = bs3;
            dot4(wi0, wi1, wi2, wi3, inring + (size_t)(t & (RING - 1)) * SLOT_STRIDE, b, A);
        }

        /* phase 2: own recurrence (sibling flags have had time to propagate) */
        if (t > 0) {
            poll256(prog_own, t, b);
            dot4(wh0, wh1, wh2, wh3, myring + (size_t)((t - 1) & (RING - 1)) * SLOT_STRIDE, b, A);
        }

        const float ig = sigmoidf_(A.x);
        const float fg = sigmoidf_(A.y);
        const float gg = tanhf_(A.z);
        const float og = sigmoidf_(A.w);
        c = fg * c + ig * gg;
        const float h = og * tanhf_(c);

        st_agent(&myring[(size_t)(t & (RING - 1)) * SLOT_STRIDE + (size_t)j * BB + b], h);
        if (b == 0) st_flag_rel(&prog_own[j], t + 1);   /* release: waits wave's h store */
    }
}

/* ---------------- Kernel 3: FC head on h2[T-1] ([k][b] layout) ---------------- */
__global__ __launch_bounds__(256) void classifier_k(
    const float* __restrict__ hring,
    const float* __restrict__ W1, const float* __restrict__ bfc1,
    const float* __restrict__ W2, const float* __restrict__ bfc2,
    float* __restrict__ out)
{
    __shared__ float z[BB * 128];
    const float* h2T = hring + 2 * LAYER_STRIDE + (size_t)((TT - 1) & (RING - 1)) * SLOT_STRIDE;
    const int tid = threadIdx.x;
    for (int idx = tid; idx < BB * 128; idx += 256) {
        const int bb = idx >> 7;
        const int n = idx & 127;
        float acc = bfc1[n];
        const float* wr = W1 + (size_t)n * HD;
        for (int k = 0; k < HD; ++k)
            acc = fmaf(h2T[k * BB + bb], wr[k], acc);
        z[bb * 128 + n] = fmaxf(acc, 0.0f);
    }
    __syncthreads();
    for (int idx = tid; idx < BB * NCLS; idx += 256) {
        const int bb = idx >> 3;
        const int n = idx & 7;
        float acc = bfc2[n];
        const float* zr = &z[bb * 128];
        const float* wr = W2 + (size_t)n * 128;
        for (int k = 0; k < 128; k += 4) {
            const float4 zv = *(const float4*)&zr[k];
            const float4 wv = *(const float4*)&wr[k];
            acc = fmaf(zv.x, wv.x, acc); acc = fmaf(zv.y, wv.y, acc);
            acc = fmaf(zv.z, wv.z, acc); acc = fmaf(zv.w, wv.w, acc);
        }
        out[idx] = acc;
    }
}

extern "C" void kernel_launch(void* const* d_in, const int* in_sizes, int n_in,
                              void* d_out, int out_size, void* d_ws, size_t ws_size,
                              hipStream_t stream) {
    const float* x    = (const float*)d_in[0];
    const float* Wih0 = (const float*)d_in[1];
    const float* Whh0 = (const float*)d_in[2];
    const float* b0   = (const float*)d_in[3];
    const float* Wih1 = (const float*)d_in[4];
    const float* Whh1 = (const float*)d_in[5];
    const float* b1   = (const float*)d_in[6];
    const float* Wih2 = (const float*)d_in[7];
    const float* Whh2 = (const float*)d_in[8];
    const float* b2   = (const float*)d_in[9];
    const float* W1   = (const float*)d_in[10];
    const float* bfc1 = (const float*)d_in[11];
    const float* W2   = (const float*)d_in[12];
    const float* bfc2 = (const float*)d_in[13];

    float* xgX   = (float*)d_ws;                       // T*4H*B fp32 = 134.2 MB
    float* hring = xgX + (size_t)TT * G4H * BB;        // 3*16*16384 fp32 = 3.1 MB
    int*   prog  = (int*)(hring + 3 * LAYER_STRIDE);   // 3*256 ints

    xg0_gemm<<<dim3(G4H / GBN, (BB * TT) / GBM), 256, 0, stream>>>(x, Wih0, b0, xgX);

    const float* xgc = xgX;
    float* hr = hring;
    int* pr = prog;
    void* args[] = {
        (void*)&xgc, (void*)&Whh0,
        (void*)&Wih1, (void*)&Whh1, (void*)&b1,
        (void*)&Wih2, (void*)&Whh2, (void*)&b2,
        (void*)&hr, (void*)&pr
    };
    hipLaunchCooperativeKernel((void*)lstm_cells, dim3(192), dim3(256), args, 0, stream);

    classifier_k<<<1, 256, 0, stream>>>(hring, W1, bfc1, W2, bfc2, (float*)d_out);
}